// Round 2
// baseline (79.808 us; speedup 1.0000x reference)
//
#include <hip/hip_runtime.h>
#include <hip/hip_bf16.h>

// VQ-VAE quantize: x[32,64,64,64] NCHW fp32, codebook[512,64] fp32.
// out[0] = 1.25*SSD/8388608 ; out[1..] = codebook[argmin] in NCHW.
// R2: 128-row tiles (4 blocks/CU), codebook quarters with reg-prefetch,
// loss fused via SSD = sum(x^2) - 2*sum(bestv)  (no phase-B x re-read).

typedef __attribute__((ext_vector_type(8))) __bf16 bf16x8;
typedef __attribute__((ext_vector_type(4))) float f32x4;

#define XA_OFF   0
#define CB_OFF   16384
#define HN2_OFF  32768
#define IDX_OFF  34816
#define RED_OFF  35328
#define SMEM_SZ  35840

__device__ __forceinline__ unsigned f2b1(float f) {
  unsigned u = __float_as_uint(f);
  return (u + 0x7FFFu + ((u >> 16) & 1)) >> 16;   // RNE float->bf16 bits
}
__device__ __forceinline__ unsigned pack2(float lo, float hi) {
  return f2b1(lo) | (f2b1(hi) << 16);
}
__device__ __forceinline__ int swz(int row) {    // XOR swizzle, 16B granules
  return ((row & 7) ^ ((row >> 4) & 7)) << 4;
}

__global__ void __launch_bounds__(256, 4)
vq_main(const float* __restrict__ x, const float* __restrict__ cb,
        float* __restrict__ out, float* __restrict__ ws) {
  __shared__ __align__(16) char smem[SMEM_SZ];
  char*  xaz  = smem + XA_OFF;            // bf16 [128][64] swizzled
  char*  cbz  = smem + CB_OFF;            // bf16 [128 codes][64] swizzled
  float* hn2z = (float*)(smem + HN2_OFF); // -0.5*||c||^2 for 512 codes
  int*   idxz = (int*)(smem + IDX_OFF);   // [128]
  float* redz = (float*)(smem + RED_OFF); // [4]
  float* qld  = (float*)smem;             // phase-B overlay: fp32 [128][65]

  const int t    = threadIdx.x;
  const int bid  = blockIdx.x;
  const int bimg = bid >> 5;              // batch index
  const int hw0  = (bid & 31) << 7;       // 128-row hw tile start
  const float4* xb4 = (const float4*)(x + (bimg << 18) + hw0);
  const float4* cb4 = (const float4*)cb;

  const int ccid = t >> 1;                // local code 0..127
  const int chh  = t & 1;                 // d-half (0: d 0..31, 1: d 32..63)

  // ---- prefetch codebook quarter 0 into regs ----
  float4 f[8];
  #pragma unroll
  for (int j = 0; j < 8; ++j) f[j] = cb4[(ccid << 4) + (chh << 3) + j];

  // ---- stage X tile (transpose to bf16 [row][d] swizzled) + sum x^2 ----
  float xsq = 0.f;
  {
    const int p  = t >> 3;                // d-pair 0..31
    const int r0 = (t & 7) << 4;          // row group
    #pragma unroll
    for (int j = 0; j < 4; ++j) {
      float4 A0 = xb4[((2 * p) << 10) + (r0 >> 2) + j];
      float4 A1 = xb4[((2 * p + 1) << 10) + (r0 >> 2) + j];
      const float* a0 = (const float*)&A0;
      const float* a1 = (const float*)&A1;
      #pragma unroll
      for (int u = 0; u < 4; ++u) {
        xsq = fmaf(a0[u], a0[u], xsq);
        xsq = fmaf(a1[u], a1[u], xsq);
        int r = r0 + (j << 2) + u;
        *(unsigned*)(xaz + r * 128 + ((p << 2) ^ swz(r))) = pack2(a0[u], a1[u]);
      }
    }
  }

  // ---- write codebook quarter 0 to LDS + hn2 ----
  {
    float s = 0.f;
    unsigned us[16];
    #pragma unroll
    for (int j = 0; j < 8; ++j) {
      s += f[j].x * f[j].x + f[j].y * f[j].y + f[j].z * f[j].z + f[j].w * f[j].w;
      us[2 * j]     = pack2(f[j].x, f[j].y);
      us[2 * j + 1] = pack2(f[j].z, f[j].w);
    }
    float sf = s + __shfl_xor(s, 1, 64);
    if (chh == 0) hn2z[ccid] = -0.5f * sf;
    const int sw = swz(ccid);
    #pragma unroll
    for (int jj = 0; jj < 4; ++jj) {
      uint4 u4 = {us[4 * jj], us[4 * jj + 1], us[4 * jj + 2], us[4 * jj + 3]};
      *(uint4*)(cbz + ccid * 128 + ((((chh << 6) + (jj << 4))) ^ sw)) = u4;
    }
  }
  __syncthreads();

  const int lane = t & 63;
  const int wid  = t >> 6;
  const int lrow = lane & 15;
  const int lk2  = (lane >> 4) << 4;

  // A fragments persist in regs (2 subtiles x 2 k-steps)
  bf16x8 af[2][2];
  #pragma unroll
  for (int s = 0; s < 2; ++s) {
    int row = (wid << 5) + (s << 4) + lrow;
    int sw = swz(row);
    af[s][0] = *(const bf16x8*)(xaz + row * 128 + (lk2 ^ sw));
    af[s][1] = *(const bf16x8*)(xaz + row * 128 + ((lk2 ^ 64) ^ sw));
  }

  float bestv[2][4];
  int   besti[2][4];
  #pragma unroll
  for (int s = 0; s < 2; ++s)
    #pragma unroll
    for (int r = 0; r < 4; ++r) { bestv[s][r] = -3.0e38f; besti[s][r] = 0; }

  for (int q = 0; q < 4; ++q) {
    if (q < 3) {  // prefetch next quarter while MFMA runs
      #pragma unroll
      for (int j = 0; j < 8; ++j)
        f[j] = cb4[(((q + 1) << 7) + ccid) * 16 + (chh << 3) + j];
    }
    #pragma unroll
    for (int c = 0; c < 8; ++c) {
      const int crow = (c << 4) + lrow;
      const int co = lk2 ^ ((lrow & 7) << 4) ^ (c << 4);
      bf16x8 b0 = *(const bf16x8*)(cbz + crow * 128 + co);
      bf16x8 b1 = *(const bf16x8*)(cbz + crow * 128 + (co ^ 64));
      const int nc = (q << 7) + crow;
      const float hv = hn2z[nc];
      #pragma unroll
      for (int s = 0; s < 2; ++s) {
        f32x4 acc = {hv, hv, hv, hv};
        acc = __builtin_amdgcn_mfma_f32_16x16x32_bf16(af[s][0], b0, acc, 0, 0, 0);
        acc = __builtin_amdgcn_mfma_f32_16x16x32_bf16(af[s][1], b1, acc, 0, 0, 0);
        #pragma unroll
        for (int r = 0; r < 4; ++r) {
          if (acc[r] > bestv[s][r]) { bestv[s][r] = acc[r]; besti[s][r] = nc; }
        }
      }
    }
    if (q < 3) {
      __syncthreads();                    // all waves done reading quarter q
      float s = 0.f;
      unsigned us[16];
      #pragma unroll
      for (int j = 0; j < 8; ++j) {
        s += f[j].x * f[j].x + f[j].y * f[j].y + f[j].z * f[j].z + f[j].w * f[j].w;
        us[2 * j]     = pack2(f[j].x, f[j].y);
        us[2 * j + 1] = pack2(f[j].z, f[j].w);
      }
      float sf = s + __shfl_xor(s, 1, 64);
      if (chh == 0) hn2z[((q + 1) << 7) + ccid] = -0.5f * sf;
      const int sw = swz(ccid);
      #pragma unroll
      for (int jj = 0; jj < 4; ++jj) {
        uint4 u4 = {us[4 * jj], us[4 * jj + 1], us[4 * jj + 2], us[4 * jj + 3]};
        *(uint4*)(cbz + ccid * 128 + ((((chh << 6) + (jj << 4))) ^ sw)) = u4;
      }
      __syncthreads();
    }
  }

  // ---- cross-lane argmax (over the 16 code column slots) + loss partial ----
  float vsum = 0.f;
  #pragma unroll
  for (int s = 0; s < 2; ++s) {
    #pragma unroll
    for (int r = 0; r < 4; ++r) {
      float v = bestv[s][r];
      int  id = besti[s][r];
      #pragma unroll
      for (int m = 1; m <= 8; m <<= 1) {
        float pv = __shfl_xor(v, m, 64);
        int   pi = __shfl_xor(id, m, 64);
        if (pv > v || (pv == v && pi < id)) { v = pv; id = pi; }
      }
      if (lrow == 0) {
        idxz[(wid << 5) + (s << 4) + ((lane >> 4) << 2) + r] = id;
        vsum += v;
      }
    }
  }
  float lacc = xsq - 2.0f * vsum;
  #pragma unroll
  for (int m = 32; m; m >>= 1) lacc += __shfl_xor(lacc, m, 64);
  if (lane == 0) redz[wid] = lacc;
  __syncthreads();                        // idx+red ready; xaz/cbz dead
  if (t == 0) ws[bid] = redz[0] + redz[1] + redz[2] + redz[3];

  // ---- phase B: gather code rows, transpose via LDS, coalesced NCHW write --
  {
    const int myrow = t >> 1;
    const int myidx = idxz[myrow];
    float4 g[8];
    #pragma unroll
    for (int j = 0; j < 8; ++j) g[j] = cb4[(myidx << 4) + (chh << 3) + j];
    float* qrow = qld + myrow * 65 + (chh << 5);
    #pragma unroll
    for (int j = 0; j < 8; ++j) {
      qrow[4 * j + 0] = g[j].x; qrow[4 * j + 1] = g[j].y;
      qrow[4 * j + 2] = g[j].z; qrow[4 * j + 3] = g[j].w;
    }
  }
  __syncthreads();
  {
    float* outq = out + 1 + (bimg << 18) + hw0;
    const int r = t & 127;
    const int dbase = t >> 7;
    #pragma unroll
    for (int i = 0; i < 32; ++i) {
      const int d = dbase + (i << 1);
      outq[(d << 12) + r] = qld[r * 65 + d];
    }
  }
}

__global__ void vq_finalize(const float* __restrict__ ws, float* __restrict__ out) {
  int t = threadIdx.x;
  __shared__ float red[4];
  float v = ws[t] + ws[t + 256] + ws[t + 512] + ws[t + 768];
  #pragma unroll
  for (int m = 32; m; m >>= 1) v += __shfl_xor(v, m, 64);
  if ((t & 63) == 0) red[t >> 6] = v;
  __syncthreads();
  if (t == 0) out[0] = (red[0] + red[1] + red[2] + red[3]) * (1.25f / 8388608.0f);
}

extern "C" void kernel_launch(void* const* d_in, const int* in_sizes, int n_in,
                              void* d_out, int out_size, void* d_ws, size_t ws_size,
                              hipStream_t stream) {
  const float* x  = (const float*)d_in[0];   // 32*64*64*64 fp32 NCHW
  const float* cb = (const float*)d_in[1];   // 512*64 fp32
  float* out = (float*)d_out;                // [0]=loss, [1..]=quantized NCHW
  float* ws  = (float*)d_ws;                 // 1024 partial loss sums
  vq_main<<<1024, 256, 0, stream>>>(x, cb, out, ws);
  vq_finalize<<<1, 256, 0, stream>>>(ws, out);
}